// Round 5
// baseline (186.169 us; speedup 1.0000x reference)
//
#include <hip/hip_runtime.h>
#include <hip/hip_bf16.h>
#include <math.h>

// ---------------------------------------------------------------------------
// GCN 2-layer forward on MI355X.  ZERO global atomics.  5 launches.
//  FUSED [hist_lds (512 blocks = 128 chunks x 4 node-quarters, 12.5KB LDS
//         byte-packed histograms (4 nodes/word), rank via LDS-atomic return)
//         || convw (W->bf16^T pair-permuted)]
//  -> scan2 (sum 128 replicas/node -> basecum uint8, dinv, degs, 8-padded
//            exscan, blocksum)
//  -> FUSED [fill_csr (LDS-scan blocksums; offsets; scatter; pad slots ->
//            dummy node N) || mfma_gemm1 (x @ W1t, *dinv, bf16 h1; zero row N)]
//  -> FUSED [agg1 (4 waves/block, 4 nodes/wave, tail-free 16/8-deep gather
//            w/ uint4 index loads -> LDS) + mfma_gemm2 tail (zero h2 row N)]
//  -> agg2 (1 node/WAVE, half-waves split the 8-edge blocks, shfl_xor(32)
//            combine; + b2 + log_softmax)
// R6-R8: global atomics pinned ~1.6e10/s (HW wall) -> LDS atomics only.
// R10: fused convw+hist.  R11: finalize->fill; gemm2->agg1.  R12: 8-deep,
// 2 nodes/wave.  R13: 256-thr blocks 8/CU (occupancy-doubling only -10% =>
// gather near ~5.5 TB/s logical fabric ceiling).  R14: %8-padded CSR, uint4
// index loads, 16-deep, hist quarter-split (180.0us).
// R15: counts/basecum/rank byte-packed (deg<<255: ~20MB preproc traffic cut);
//      agg2 one-node-per-wave (kills intra-wave divergence, halves trips).
// ---------------------------------------------------------------------------

typedef unsigned int uint32;
typedef unsigned short ushort16;
typedef unsigned char uchar;
typedef __attribute__((ext_vector_type(8))) short bf16x8;
typedef __attribute__((ext_vector_type(4))) float f32x4;

__device__ inline unsigned short f2bf_rne(float f) {
    uint32 x = __float_as_uint(f);
    uint32 r = (x + 0x7fffu + ((x >> 16) & 1u)) >> 16;
    return (unsigned short)r;
}
__device__ inline uint32 pack_bf16x2(float a, float b) {
    return (uint32)f2bf_rne(a) | ((uint32)f2bf_rne(b) << 16);
}
__device__ inline float2 unpack_bf16x2(uint32 u) {
    float2 r;
    r.x = __uint_as_float(u << 16);
    r.y = __uint_as_float(u & 0xffff0000u);
    return r;
}

#define NHB 128  // histogram chunks / replicas

// FUSED: blocks [0,4*NHB): per-(chunk,node-quarter) LDS histogram, 4 nodes
//   byte-packed per word (per-chunk per-node count <= ~6 << 255), rank =
//   LDS-atomic old byte; dump slice to counts_pb ([b][w] linear).
// blocks [4*NHB, 4*NHB+CB): convw — W -> bf16 transposed, pair-permuted.
__global__ __launch_bounds__(256) void hist_conv_k(const int* __restrict__ dst, int E,
                                                   int NWb, int chunk,
                                                   uint32* __restrict__ counts_pb,
                                                   uchar* __restrict__ rankx,
                                                   const float* __restrict__ W1,
                                                   const float* __restrict__ W2,
                                                   unsigned short* __restrict__ W1t,
                                                   unsigned short* __restrict__ W2t) {
    const int tid = threadIdx.x;
    if ((int)blockIdx.x >= 4 * NHB) {
        int idx = ((int)blockIdx.x - 4 * NHB) * 256 + tid;
        if (idx < 128 * 128) {
            int ns = idx >> 7, k = idx & 127;
            int t = ns >> 4, m = ns & 15;
            int col = 32 * (t >> 1) + 2 * m + (t & 1);
            W1t[idx] = f2bf_rne(W1[k * 128 + col]);
        } else {
            int i2 = idx - 128 * 128;
            if (i2 < 64 * 128) {
                int ns = i2 >> 7, k = i2 & 127;
                int t = ns >> 4, m = ns & 15;
                int col = 32 * (t >> 1) + 2 * m + (t & 1);
                W2t[i2] = f2bf_rne(W2[k * 64 + col]);
            }
        }
        return;
    }
    extern __shared__ uint32 sh[];
    const int hb  = blockIdx.x >> 2;
    const int qt  = blockIdx.x & 3;
    const int NWq = (NWb + 3) >> 2;
    const int qlo = qt * NWq;
    const int qhi = min(NWb, qlo + NWq);
    const int qn  = qhi - qlo;
    for (int i = tid; i < qn; i += 256) sh[i] = 0;
    __syncthreads();
    const int e0 = hb * chunk;
    const int e1 = min(E, e0 + chunk);
    int e = e0 + tid;
    for (; e + 768 < e1; e += 1024) {
        int d0 = dst[e];
        int d1 = dst[e + 256];
        int d2 = dst[e + 512];
        int d3 = dst[e + 768];
        int w0 = d0 >> 2, w1 = d1 >> 2, w2 = d2 >> 2, w3 = d3 >> 2;
        if (w0 >= qlo && w0 < qhi) {
            uint32 o = atomicAdd(&sh[w0 - qlo], 1u << (8 * (d0 & 3)));
            rankx[e] = (uchar)(o >> (8 * (d0 & 3)));
        }
        if (w1 >= qlo && w1 < qhi) {
            uint32 o = atomicAdd(&sh[w1 - qlo], 1u << (8 * (d1 & 3)));
            rankx[e + 256] = (uchar)(o >> (8 * (d1 & 3)));
        }
        if (w2 >= qlo && w2 < qhi) {
            uint32 o = atomicAdd(&sh[w2 - qlo], 1u << (8 * (d2 & 3)));
            rankx[e + 512] = (uchar)(o >> (8 * (d2 & 3)));
        }
        if (w3 >= qlo && w3 < qhi) {
            uint32 o = atomicAdd(&sh[w3 - qlo], 1u << (8 * (d3 & 3)));
            rankx[e + 768] = (uchar)(o >> (8 * (d3 & 3)));
        }
    }
    for (; e < e1; e += 256) {
        int d = dst[e];
        int w = d >> 2;
        if (w >= qlo && w < qhi) {
            uint32 o = atomicAdd(&sh[w - qlo], 1u << (8 * (d & 3)));
            rankx[e] = (uchar)(o >> (8 * (d & 3)));
        }
    }
    __syncthreads();
    uint32* dstp = counts_pb + (size_t)hb * NWb + qlo;
    for (int i = tid; i < qn; i += 256) dstp[i] = sh[i];
}

// Sum per-node byte counts over NHB chunk-histograms (16-way batched loads),
// emit basecum[b][n] (uint8), dinv, degs, 8-PADDED block-local exscan +
// blocksum (CSR segments padded to %8 for aligned tail-free gathers).
__global__ __launch_bounds__(256) void scan2_k(const uint32* __restrict__ counts_pb,
                                               int N, int NWb,
                                               uchar* __restrict__ basecum,
                                               int* __restrict__ exscan,
                                               int* __restrict__ blocksum,
                                               float* __restrict__ dinv,
                                               ushort16* __restrict__ degs) {
    __shared__ int sd[256];
    const int tid = threadIdx.x;
    const int n   = blockIdx.x * 256 + tid;
    const int nc  = n < N ? n : N - 1;
    const int wq  = nc >> 2;
    const int sh8 = 8 * (nc & 3);
    int cum = 0;
    for (int bb = 0; bb < NHB; bb += 16) {
        uint32 wv[16];
#pragma unroll
        for (int j = 0; j < 16; ++j)
            wv[j] = counts_pb[(size_t)(bb + j) * NWb + wq];
#pragma unroll
        for (int j = 0; j < 16; ++j) {
            int c = (int)((wv[j] >> sh8) & 0xffu);
            if (n < N) basecum[(size_t)(bb + j) * N + n] = (uchar)cum;
            cum += c;
        }
    }
    int v = (n < N) ? cum : 0;
    if (n < N) {
        dinv[n] = rsqrtf((float)(v + 1));
        degs[n] = (ushort16)v;
    }
    int vp = (v + 7) & ~7;  // padded segment length
    sd[tid] = vp;
    __syncthreads();
    for (int off = 1; off < 256; off <<= 1) {
        int t = (tid >= off) ? sd[tid - off] : 0;
        __syncthreads();
        sd[tid] += t;
        __syncthreads();
    }
    if (n < N) exscan[n] = sd[tid] - vp;
    if (tid == 255) blocksum[blockIdx.x] = sd[255];
}

// FUSED: blocks [0,256): fill CSR (ushort src).  Each fill block LDS-scans
//   the (<=256) blocksums -> ebs[], writes its offsets slice AND the pad
//   slots (dummy node N -> zero rows), then scatters:
//     pos = ebs[d>>8] + exscan[d] + basecum[b][d] + rank.
// blocks [256,256+GB): mfma gemm1 h1 = bf16((x @ W1t) * dinv); zeroes row N.
__global__ __launch_bounds__(256) void fill_gemm1_k(const int* __restrict__ src,
                                                    const int* __restrict__ dst, int E,
                                                    int chunk, int N,
                                                    const uchar* __restrict__ rankx,
                                                    const uchar* __restrict__ basecum,
                                                    const int* __restrict__ blocksum,
                                                    int NB,
                                                    const int* __restrict__ exscan,
                                                    const ushort16* __restrict__ degs,
                                                    int* __restrict__ offsets,
                                                    ushort16* __restrict__ csr_src,
                                                    const float* __restrict__ X,
                                                    const unsigned short* __restrict__ Wt,
                                                    const float* __restrict__ dinv,
                                                    uint32* __restrict__ Yu, int Nrows) {
    __shared__ int sd[256];
    __shared__ int ebs[256];
    __shared__ int total;
    if ((int)blockIdx.x < 256) {
        const int f   = blockIdx.x;
        const int tid = threadIdx.x;
        // ---- redundant 196-element scan of blocksums (cheap) ----
        int v = (tid < NB) ? blocksum[tid] : 0;
        sd[tid] = v;
        __syncthreads();
        for (int off = 1; off < 256; off <<= 1) {
            int t = (tid >= off) ? sd[tid - off] : 0;
            __syncthreads();
            sd[tid] += t;
            __syncthreads();
        }
        ebs[tid] = sd[tid] - v;
        if (tid == 255) total = sd[255];
        __syncthreads();
        // ---- offsets slice + pad slots for the downstream agg kernels ----
        int g = f * 256 + tid;
        if (g < N) {
            int off = ebs[g >> 8] + exscan[g];
            offsets[g] = off;
            int dg = degs[g];
            int pl = (dg + 7) & ~7;
            for (int k = dg; k < pl; ++k) csr_src[off + k] = (ushort16)N;
        } else if (g == N) {
            offsets[N] = total;
        }
        // ---- CSR scatter ----
        const int b  = f >> 1;
        const uchar* bc = basecum + (size_t)b * N;
        const int q2 = chunk >> 1;
        const int e0 = b * chunk + (f & 1) * q2;
        const int e1 = min(E, e0 + q2);
        int e = e0 + tid;
        for (; e + 768 < e1; e += 1024) {
#pragma unroll
            for (int j = 0; j < 4; ++j) {
                int ej = e + j * 256;
                int d = dst[ej];
                int pos = ebs[d >> 8] + exscan[d] + (int)bc[d] + (int)rankx[ej];
                csr_src[pos] = (ushort16)src[ej];
            }
        }
        for (; e < e1; e += 256) {
            int d = dst[e];
            int pos = ebs[d >> 8] + exscan[d] + (int)bc[d] + (int)rankx[e];
            csr_src[pos] = (ushort16)src[e];
        }
        return;
    }
    // ---- gemm1 part (NCOL=128, fp32 A converted in-register, *dinv) ----
    constexpr int NCOL = 128;
    constexpr int NT = NCOL / 16;
    const int tid  = threadIdx.x;
    const int wave = tid >> 6;
    const int lane = tid & 63;
    const int m16  = lane & 15;
    const int q    = lane >> 4;
    const int r0   = ((int)blockIdx.x - 256) * 64 + wave * 16;

    // dummy zero row N for CSR pads (one wave, once)
    if ((int)blockIdx.x == 256 && tid < 64) Yu[(size_t)Nrows * (NCOL / 2) + tid] = 0;

    int arow = r0 + m16;
    if (arow >= Nrows) arow = Nrows - 1;

    bf16x8 afrag[4];
#pragma unroll
    for (int kb = 0; kb < 4; ++kb) {
        const float* p = &X[(size_t)arow * 128 + kb * 32 + q * 8];
        float4 u0 = *(const float4*)p;
        float4 u1 = *(const float4*)(p + 4);
        bf16x8 a;
        a[0] = (short)f2bf_rne(u0.x); a[1] = (short)f2bf_rne(u0.y);
        a[2] = (short)f2bf_rne(u0.z); a[3] = (short)f2bf_rne(u0.w);
        a[4] = (short)f2bf_rne(u1.x); a[5] = (short)f2bf_rne(u1.y);
        a[6] = (short)f2bf_rne(u1.z); a[7] = (short)f2bf_rne(u1.w);
        afrag[kb] = a;
    }

    f32x4 acc[NT];
#pragma unroll
    for (int t = 0; t < NT; ++t) acc[t] = (f32x4){0.f, 0.f, 0.f, 0.f};
#pragma unroll
    for (int t = 0; t < NT; ++t) {
        const unsigned short* Bp = &Wt[(size_t)(t * 16 + m16) * 128 + q * 8];
#pragma unroll
        for (int kb = 0; kb < 4; ++kb) {
            bf16x8 bfrag = *(const bf16x8*)&Bp[kb * 32];
            acc[t] = __builtin_amdgcn_mfma_f32_16x16x32_bf16(afrag[kb], bfrag, acc[t], 0, 0, 0);
        }
    }
#pragma unroll
    for (int i = 0; i < 4; ++i) {
        int row = r0 + q * 4 + i;
        if (row < Nrows) {
            float dn = dinv[row];
#pragma unroll
            for (int u = 0; u < NT / 2; ++u)
                Yu[(size_t)row * (NCOL / 2) + u * 16 + m16] =
                    pack_bf16x2(acc[2 * u][i] * dn, acc[2 * u + 1][i] * dn);
        }
    }
}

// FUSED layer-1 aggregation + gemm2.
// 256 threads = 4 waves; wave w aggregates nodes base+4w..base+4w+3.
// CSR segments are %8-padded (pads -> zero row N) so the gather loop is
// tail-free: 16-deep then 8-deep, indices loaded as uint4 (8 per load).
// After the barrier, waves 0-1 compute the 16x64 gemm2 tile (W2t
// pair-permuted) and write h2 with dinv folded.  Block 0 zeroes h2 row N.
__global__ __launch_bounds__(256, 8) void agg1_gemm2_k(const unsigned short* __restrict__ hs,
                                                       const int* __restrict__ offsets,
                                                       const ushort16* __restrict__ csr_src,
                                                       const float* __restrict__ dinv,
                                                       const float* __restrict__ b1,
                                                       const unsigned short* __restrict__ W2t,
                                                       uint32* __restrict__ Yu, int N) {
    __shared__ uint32 srow[16 * 68];
    const int tid  = threadIdx.x;
    const int w    = tid >> 6;
    const int lane = tid & 63;
    const int base = (int)blockIdx.x * 16;
    const uint32* T = (const uint32*)hs;
    const float2 bb = ((const float2*)b1)[lane];
    // dummy zero row N of h2 for agg2's padded gathers (one wave, once)
    if (blockIdx.x == 0 && w == 2 && lane < 32) Yu[(size_t)N * 32 + lane] = 0;
#pragma unroll
    for (int which = 0; which < 4; ++which) {
        const int node = base + 4 * w + which;
        uint32 packed = 0;
        if (node < N) {
            const int start = offsets[node];
            const int end   = offsets[node + 1];
            const float dn  = dinv[node];
            float2 self = unpack_bf16x2(T[(size_t)node * 64 + lane]);
            float ax0 = self.x, ay0 = self.y;
            float ax1 = 0.f, ay1 = 0.f, ax2 = 0.f, ay2 = 0.f, ax3 = 0.f, ay3 = 0.f;
            int p = start;
            for (; p + 15 < end; p += 16) {
                uint4 ia = *(const uint4*)&csr_src[p];
                uint4 ib = *(const uint4*)&csr_src[p + 8];
                int s0 = ia.x & 0xffff, s1 = ia.x >> 16;
                int s2 = ia.y & 0xffff, s3 = ia.y >> 16;
                int s4 = ia.z & 0xffff, s5 = ia.z >> 16;
                int s6 = ia.w & 0xffff, s7 = ia.w >> 16;
                int s8 = ib.x & 0xffff, s9 = ib.x >> 16;
                int sa = ib.y & 0xffff, sb = ib.y >> 16;
                int sc = ib.z & 0xffff, sd = ib.z >> 16;
                int se = ib.w & 0xffff, sf = ib.w >> 16;
                uint32 u0 = T[(size_t)s0 * 64 + lane];
                uint32 u1 = T[(size_t)s1 * 64 + lane];
                uint32 u2 = T[(size_t)s2 * 64 + lane];
                uint32 u3 = T[(size_t)s3 * 64 + lane];
                uint32 u4 = T[(size_t)s4 * 64 + lane];
                uint32 u5 = T[(size_t)s5 * 64 + lane];
                uint32 u6 = T[(size_t)s6 * 64 + lane];
                uint32 u7 = T[(size_t)s7 * 64 + lane];
                uint32 u8 = T[(size_t)s8 * 64 + lane];
                uint32 u9 = T[(size_t)s9 * 64 + lane];
                uint32 ua = T[(size_t)sa * 64 + lane];
                uint32 ub = T[(size_t)sb * 64 + lane];
                uint32 uc = T[(size_t)sc * 64 + lane];
                uint32 ud = T[(size_t)sd * 64 + lane];
                uint32 ue = T[(size_t)se * 64 + lane];
                uint32 uf = T[(size_t)sf * 64 + lane];
                float2 f0 = unpack_bf16x2(u0), f1 = unpack_bf16x2(u1);
                float2 f2 = unpack_bf16x2(u2), f3 = unpack_bf16x2(u3);
                float2 f4 = unpack_bf16x2(u4), f5 = unpack_bf16x2(u5);
                float2 f6 = unpack_bf16x2(u6), f7 = unpack_bf16x2(u7);
                float2 f8 = unpack_bf16x2(u8), f9 = unpack_bf16x2(u9);
                float2 fa = unpack_bf16x2(ua), fb = unpack_bf16x2(ub);
                float2 fc = unpack_bf16x2(uc), fd = unpack_bf16x2(ud);
                float2 fe = unpack_bf16x2(ue), ff = unpack_bf16x2(uf);
                ax0 += (f0.x + f4.x) + (f8.x + fc.x);
                ay0 += (f0.y + f4.y) + (f8.y + fc.y);
                ax1 += (f1.x + f5.x) + (f9.x + fd.x);
                ay1 += (f1.y + f5.y) + (f9.y + fd.y);
                ax2 += (f2.x + f6.x) + (fa.x + fe.x);
                ay2 += (f2.y + f6.y) + (fa.y + fe.y);
                ax3 += (f3.x + f7.x) + (fb.x + ff.x);
                ay3 += (f3.y + f7.y) + (fb.y + ff.y);
            }
            for (; p + 7 < end; p += 8) {
                uint4 ia = *(const uint4*)&csr_src[p];
                int s0 = ia.x & 0xffff, s1 = ia.x >> 16;
                int s2 = ia.y & 0xffff, s3 = ia.y >> 16;
                int s4 = ia.z & 0xffff, s5 = ia.z >> 16;
                int s6 = ia.w & 0xffff, s7 = ia.w >> 16;
                uint32 u0 = T[(size_t)s0 * 64 + lane];
                uint32 u1 = T[(size_t)s1 * 64 + lane];
                uint32 u2 = T[(size_t)s2 * 64 + lane];
                uint32 u3 = T[(size_t)s3 * 64 + lane];
                uint32 u4 = T[(size_t)s4 * 64 + lane];
                uint32 u5 = T[(size_t)s5 * 64 + lane];
                uint32 u6 = T[(size_t)s6 * 64 + lane];
                uint32 u7 = T[(size_t)s7 * 64 + lane];
                float2 f0 = unpack_bf16x2(u0), f1 = unpack_bf16x2(u1);
                float2 f2 = unpack_bf16x2(u2), f3 = unpack_bf16x2(u3);
                float2 f4 = unpack_bf16x2(u4), f5 = unpack_bf16x2(u5);
                float2 f6 = unpack_bf16x2(u6), f7 = unpack_bf16x2(u7);
                ax0 += f0.x + f4.x; ay0 += f0.y + f4.y;
                ax1 += f1.x + f5.x; ay1 += f1.y + f5.y;
                ax2 += f2.x + f6.x; ay2 += f2.y + f6.y;
                ax3 += f3.x + f7.x; ay3 += f3.y + f7.y;
            }
            float vx = ((ax0 + ax1) + (ax2 + ax3)) * dn + bb.x;
            float vy = ((ay0 + ay1) + (ay2 + ay3)) * dn + bb.y;
            vx = vx > 0.f ? vx : 0.f;
            vy = vy > 0.f ? vy : 0.f;
            packed = pack_bf16x2(vx, vy);
        }
        srow[(4 * w + which) * 68 + lane] = packed;
    }
    __syncthreads();
    // ---- gemm2 tail: wave w<2 computes pack-pair pp=w (2 col-tiles) ----
    if (w < 2) {
        const int pp  = w;
        const int m16 = lane & 15;
        const int q   = lane >> 4;
        bf16x8 afrag[4];
#pragma unroll
        for (int kb = 0; kb < 4; ++kb)
            afrag[kb] = *(const bf16x8*)&srow[m16 * 68 + kb * 16 + q * 4];
        f32x4 acc0 = (f32x4){0.f, 0.f, 0.f, 0.f};
        f32x4 acc1 = (f32x4){0.f, 0.f, 0.f, 0.f};
        const unsigned short* Bp0 = &W2t[(size_t)((2 * pp) * 16 + m16) * 128 + q * 8];
        const unsigned short* Bp1 = &W2t[(size_t)((2 * pp + 1) * 16 + m16) * 128 + q * 8];
#pragma unroll
        for (int kb = 0; kb < 4; ++kb) {
            bf16x8 b0  = *(const bf16x8*)&Bp0[kb * 32];
            bf16x8 b1f = *(const bf16x8*)&Bp1[kb * 32];
            acc0 = __builtin_amdgcn_mfma_f32_16x16x32_bf16(afrag[kb], b0, acc0, 0, 0, 0);
            acc1 = __builtin_amdgcn_mfma_f32_16x16x32_bf16(afrag[kb], b1f, acc1, 0, 0, 0);
        }
#pragma unroll
        for (int i = 0; i < 4; ++i) {
            int row = base + q * 4 + i;
            if (row < N) {
                float dn2 = dinv[row];
                Yu[(size_t)row * 32 + pp * 16 + m16] =
                    pack_bf16x2(acc0[i] * dn2, acc1[i] * dn2);
            }
        }
    }
}

// Layer-2 aggregation + bias + log_softmax.  ONE NODE PER WAVE: the two
// 32-lane halves split the node's %8-padded edge blocks (stride-16
// alternation), no intra-wave divergence, per-node trips halved; partial
// sums combined with shfl_xor(.,32).  4 nodes/block (256 thr).
__global__ __launch_bounds__(256, 8) void agg2_k(const unsigned short* __restrict__ hs,
                                                 const int* __restrict__ offsets,
                                                 const ushort16* __restrict__ csr_src,
                                                 const float* __restrict__ dinv,
                                                 const float* __restrict__ b2,
                                                 float* __restrict__ out, int N) {
    const int tid  = threadIdx.x;
    const int w    = tid >> 6;
    const int lane = tid & 63;
    const int half = lane >> 5;
    const int l    = lane & 31;
    const int node = blockIdx.x * 4 + w;
    if (node >= N) return;
    const uint32* T = (const uint32*)hs;
    const int start = offsets[node];
    const int end   = offsets[node + 1];
    const float dn  = dinv[node];
    float ax0 = 0.f, ay0 = 0.f;
    if (half == 0) {
        float2 self = unpack_bf16x2(T[(size_t)node * 32 + l]);
        ax0 = self.x; ay0 = self.y;
    }
    float ax1 = 0.f, ay1 = 0.f, ax2 = 0.f, ay2 = 0.f, ax3 = 0.f, ay3 = 0.f;
    for (int p = start + half * 8; p < end; p += 16) {
        uint4 ia = *(const uint4*)&csr_src[p];
        int s0 = ia.x & 0xffff, s1 = ia.x >> 16;
        int s2 = ia.y & 0xffff, s3 = ia.y >> 16;
        int s4 = ia.z & 0xffff, s5 = ia.z >> 16;
        int s6 = ia.w & 0xffff, s7 = ia.w >> 16;
        uint32 u0 = T[(size_t)s0 * 32 + l];
        uint32 u1 = T[(size_t)s1 * 32 + l];
        uint32 u2 = T[(size_t)s2 * 32 + l];
        uint32 u3 = T[(size_t)s3 * 32 + l];
        uint32 u4 = T[(size_t)s4 * 32 + l];
        uint32 u5 = T[(size_t)s5 * 32 + l];
        uint32 u6 = T[(size_t)s6 * 32 + l];
        uint32 u7 = T[(size_t)s7 * 32 + l];
        float2 f0 = unpack_bf16x2(u0), f1 = unpack_bf16x2(u1);
        float2 f2 = unpack_bf16x2(u2), f3 = unpack_bf16x2(u3);
        float2 f4 = unpack_bf16x2(u4), f5 = unpack_bf16x2(u5);
        float2 f6 = unpack_bf16x2(u6), f7 = unpack_bf16x2(u7);
        ax0 += f0.x + f4.x; ay0 += f0.y + f4.y;
        ax1 += f1.x + f5.x; ay1 += f1.y + f5.y;
        ax2 += f2.x + f6.x; ay2 += f2.y + f6.y;
        ax3 += f3.x + f7.x; ay3 += f3.y + f7.y;
    }
    float sx = (ax0 + ax1) + (ax2 + ax3);
    float sy = (ay0 + ay1) + (ay2 + ay3);
    sx += __shfl_xor(sx, 32, 64);
    sy += __shfl_xor(sy, 32, 64);
    float2 bb = ((const float2*)b2)[l];
    float vx = sx * dn + bb.x;
    float vy = sy * dn + bb.y;
    float m = fmaxf(vx, vy);
#pragma unroll
    for (int off = 16; off > 0; off >>= 1) m = fmaxf(m, __shfl_xor(m, off, 64));
    float ex = __expf(vx - m) + __expf(vy - m);
    float ssum = ex;
#pragma unroll
    for (int off = 16; off > 0; off >>= 1) ssum += __shfl_xor(ssum, off, 64);
    float lse = m + __logf(ssum);
    if (half == 0) {
        float2 o = {vx - lse, vy - lse};
        ((float2*)out)[(size_t)node * 32 + l] = o;
    }
}

extern "C" void kernel_launch(void* const* d_in, const int* in_sizes, int n_in,
                              void* d_out, int out_size, void* d_ws, size_t ws_size,
                              hipStream_t stream) {
    const float* x  = (const float*)d_in[0];
    const int*   ei = (const int*)d_in[1];
    const float* W1 = (const float*)d_in[2];
    const float* b1 = (const float*)d_in[3];
    const float* W2 = (const float*)d_in[4];
    const float* b2 = (const float*)d_in[5];
    float* out = (float*)d_out;

    const int N = in_sizes[0] / 128;  // 50000
    const int E = in_sizes[1] / 2;    // 800000
    const int* src = ei;
    const int* dst = ei + E;
    const int NB = (N + 255) / 256;        // 196
    const int NWb = (N + 3) / 4;           // 12500 byte-packed count words
    const int NWq = (NWb + 3) >> 2;        // 3125 words per quarter-histogram
    const int chunk = (E + NHB - 1) / NHB; // 6250 edges per hist chunk

    char* ws = (char*)d_ws;
    auto alloc = [&](size_t bytes) -> char* {
        char* p = ws;
        ws += (bytes + 255) & ~(size_t)255;
        return p;
    };
    unsigned short* h1  = (unsigned short*)alloc((size_t)(N + 1) * 128 * 2); // +zero row
    unsigned short* h2  = (unsigned short*)alloc((size_t)(N + 1) * 64 * 2);  // +zero row
    uint32* counts_pb = (uint32*)alloc((size_t)NHB * NWb * 4);               // 6.4MB
    uchar* basecum  = (uchar*)alloc((size_t)NHB * N);                        // 6.4MB
    uchar* rankx    = (uchar*)alloc((size_t)E);                              // 0.8MB
    ushort16* csr_src = (ushort16*)alloc(((size_t)E + 8 * (size_t)N) * 2);   // padded CSR
    float* dinv     = (float*)alloc((size_t)N * 4);
    int*   exscan   = (int*)alloc((size_t)N * 4);
    int*   blocksum = (int*)alloc((size_t)NB * 4);
    int*   offsets  = (int*)alloc((size_t)(N + 1) * 4);
    ushort16* degs  = (ushort16*)alloc((size_t)N * 2);
    unsigned short* W1t = (unsigned short*)alloc(128 * 128 * 2);
    unsigned short* W2t = (unsigned short*)alloc(64 * 128 * 2);

    const int GB = (N + 63) / 64;          // 782 gemm blocks
    const int CB = (128 * 128 + 64 * 128 + 255) / 256;  // 96 convw blocks

    hist_conv_k<<<4 * NHB + CB, 256, NWq * 4, stream>>>(dst, E, NWb, chunk, counts_pb,
                                                        rankx, W1, W2, W1t, W2t);
    scan2_k<<<NB, 256, 0, stream>>>(counts_pb, N, NWb, basecum, exscan, blocksum, dinv,
                                    degs);
    fill_gemm1_k<<<256 + GB, 256, 0, stream>>>(src, dst, E, chunk, N, rankx, basecum,
                                               blocksum, NB, exscan, degs, offsets,
                                               csr_src, x, W1t, dinv, (uint32*)h1, N);
    agg1_gemm2_k<<<(N + 15) / 16, 256, 0, stream>>>(h1, offsets, csr_src, dinv, b1,
                                                    W2t, (uint32*)h2, N);
    agg2_k<<<(N + 3) / 4, 256, 0, stream>>>(h2, offsets, csr_src, dinv, b2, out, N);
}

// Round 6
// 174.266 us; speedup vs baseline: 1.0683x; 1.0683x over previous
//
#include <hip/hip_runtime.h>
#include <hip/hip_bf16.h>
#include <math.h>

// ---------------------------------------------------------------------------
// GCN 2-layer forward on MI355X.  ZERO global atomics.  5 launches.
//  FUSED [hist_lds (512 blocks = 128 chunks x 4 node-quarters, 12.5KB LDS
//         byte-packed histograms (4 nodes/word), rank via LDS-atomic return)
//         || convw (W->bf16^T pair-permuted)]
//  -> scan2 (sum 128 replicas/node -> basecum uint8, dinv, degs, 8-padded
//            exscan, blocksum)
//  -> FUSED [fill_csr (LDS-scan blocksums; offsets; scatter; pad slots ->
//            dummy node N) || mfma_gemm1 (x @ W1t, *dinv, bf16 h1; zero row N)]
//  -> FUSED [agg1 (4 waves/block, 4 nodes/wave, tail-free 16/8-deep gather
//            w/ uint4 index loads -> LDS) + mfma_gemm2 tail (zero h2 row N)]
//  -> agg2 (32 lanes/node, 8 nodes/block, tail-free 16/8-deep)
// R6-R8: global atomics pinned ~1.6e10/s (HW wall) -> LDS atomics only.
// R10: fused convw+hist.  R11: finalize->fill; gemm2->agg1.  R12: 8-deep,
// 2 nodes/wave.  R13: 256-thr blocks 8/CU (occupancy-doubling only -10% =>
// gather near ~5.5 TB/s logical fabric ceiling).  R14: %8-padded CSR, uint4
// index loads, 16-deep, hist quarter-split (180.0us).
// R15: byte-packed counts/basecum/rank (kept: real traffic cut), BUT agg2
//      one-node-per-wave HALVED in-flight gather loads -> reverted.
// R16: agg2 back to R14 shape (8 nodes/block, 32 lanes/node, 16-deep MLP).
//      NOTE: harness fill kernels are a clock calibrator -- R15's run was
//      ~4-5% slow (fills at 5.7-5.9 vs 6.0-6.3 TB/s).
// ---------------------------------------------------------------------------

typedef unsigned int uint32;
typedef unsigned short ushort16;
typedef unsigned char uchar;
typedef __attribute__((ext_vector_type(8))) short bf16x8;
typedef __attribute__((ext_vector_type(4))) float f32x4;

__device__ inline unsigned short f2bf_rne(float f) {
    uint32 x = __float_as_uint(f);
    uint32 r = (x + 0x7fffu + ((x >> 16) & 1u)) >> 16;
    return (unsigned short)r;
}
__device__ inline uint32 pack_bf16x2(float a, float b) {
    return (uint32)f2bf_rne(a) | ((uint32)f2bf_rne(b) << 16);
}
__device__ inline float2 unpack_bf16x2(uint32 u) {
    float2 r;
    r.x = __uint_as_float(u << 16);
    r.y = __uint_as_float(u & 0xffff0000u);
    return r;
}

#define NHB 128  // histogram chunks / replicas

// FUSED: blocks [0,4*NHB): per-(chunk,node-quarter) LDS histogram, 4 nodes
//   byte-packed per word (per-chunk per-node count <= ~6 << 255), rank =
//   LDS-atomic old byte; dump slice to counts_pb ([b][w] linear).
// blocks [4*NHB, 4*NHB+CB): convw — W -> bf16 transposed, pair-permuted.
__global__ __launch_bounds__(256) void hist_conv_k(const int* __restrict__ dst, int E,
                                                   int NWb, int chunk,
                                                   uint32* __restrict__ counts_pb,
                                                   uchar* __restrict__ rankx,
                                                   const float* __restrict__ W1,
                                                   const float* __restrict__ W2,
                                                   unsigned short* __restrict__ W1t,
                                                   unsigned short* __restrict__ W2t) {
    const int tid = threadIdx.x;
    if ((int)blockIdx.x >= 4 * NHB) {
        int idx = ((int)blockIdx.x - 4 * NHB) * 256 + tid;
        if (idx < 128 * 128) {
            int ns = idx >> 7, k = idx & 127;
            int t = ns >> 4, m = ns & 15;
            int col = 32 * (t >> 1) + 2 * m + (t & 1);
            W1t[idx] = f2bf_rne(W1[k * 128 + col]);
        } else {
            int i2 = idx - 128 * 128;
            if (i2 < 64 * 128) {
                int ns = i2 >> 7, k = i2 & 127;
                int t = ns >> 4, m = ns & 15;
                int col = 32 * (t >> 1) + 2 * m + (t & 1);
                W2t[i2] = f2bf_rne(W2[k * 64 + col]);
            }
        }
        return;
    }
    extern __shared__ uint32 sh[];
    const int hb  = blockIdx.x >> 2;
    const int qt  = blockIdx.x & 3;
    const int NWq = (NWb + 3) >> 2;
    const int qlo = qt * NWq;
    const int qhi = min(NWb, qlo + NWq);
    const int qn  = qhi - qlo;
    for (int i = tid; i < qn; i += 256) sh[i] = 0;
    __syncthreads();
    const int e0 = hb * chunk;
    const int e1 = min(E, e0 + chunk);
    int e = e0 + tid;
    for (; e + 768 < e1; e += 1024) {
        int d0 = dst[e];
        int d1 = dst[e + 256];
        int d2 = dst[e + 512];
        int d3 = dst[e + 768];
        int w0 = d0 >> 2, w1 = d1 >> 2, w2 = d2 >> 2, w3 = d3 >> 2;
        if (w0 >= qlo && w0 < qhi) {
            uint32 o = atomicAdd(&sh[w0 - qlo], 1u << (8 * (d0 & 3)));
            rankx[e] = (uchar)(o >> (8 * (d0 & 3)));
        }
        if (w1 >= qlo && w1 < qhi) {
            uint32 o = atomicAdd(&sh[w1 - qlo], 1u << (8 * (d1 & 3)));
            rankx[e + 256] = (uchar)(o >> (8 * (d1 & 3)));
        }
        if (w2 >= qlo && w2 < qhi) {
            uint32 o = atomicAdd(&sh[w2 - qlo], 1u << (8 * (d2 & 3)));
            rankx[e + 512] = (uchar)(o >> (8 * (d2 & 3)));
        }
        if (w3 >= qlo && w3 < qhi) {
            uint32 o = atomicAdd(&sh[w3 - qlo], 1u << (8 * (d3 & 3)));
            rankx[e + 768] = (uchar)(o >> (8 * (d3 & 3)));
        }
    }
    for (; e < e1; e += 256) {
        int d = dst[e];
        int w = d >> 2;
        if (w >= qlo && w < qhi) {
            uint32 o = atomicAdd(&sh[w - qlo], 1u << (8 * (d & 3)));
            rankx[e] = (uchar)(o >> (8 * (d & 3)));
        }
    }
    __syncthreads();
    uint32* dstp = counts_pb + (size_t)hb * NWb + qlo;
    for (int i = tid; i < qn; i += 256) dstp[i] = sh[i];
}

// Sum per-node byte counts over NHB chunk-histograms (16-way batched loads),
// emit basecum[b][n] (uint8), dinv, degs, 8-PADDED block-local exscan +
// blocksum (CSR segments padded to %8 for aligned tail-free gathers).
__global__ __launch_bounds__(256) void scan2_k(const uint32* __restrict__ counts_pb,
                                               int N, int NWb,
                                               uchar* __restrict__ basecum,
                                               int* __restrict__ exscan,
                                               int* __restrict__ blocksum,
                                               float* __restrict__ dinv,
                                               ushort16* __restrict__ degs) {
    __shared__ int sd[256];
    const int tid = threadIdx.x;
    const int n   = blockIdx.x * 256 + tid;
    const int nc  = n < N ? n : N - 1;
    const int wq  = nc >> 2;
    const int sh8 = 8 * (nc & 3);
    int cum = 0;
    for (int bb = 0; bb < NHB; bb += 16) {
        uint32 wv[16];
#pragma unroll
        for (int j = 0; j < 16; ++j)
            wv[j] = counts_pb[(size_t)(bb + j) * NWb + wq];
#pragma unroll
        for (int j = 0; j < 16; ++j) {
            int c = (int)((wv[j] >> sh8) & 0xffu);
            if (n < N) basecum[(size_t)(bb + j) * N + n] = (uchar)cum;
            cum += c;
        }
    }
    int v = (n < N) ? cum : 0;
    if (n < N) {
        dinv[n] = rsqrtf((float)(v + 1));
        degs[n] = (ushort16)v;
    }
    int vp = (v + 7) & ~7;  // padded segment length
    sd[tid] = vp;
    __syncthreads();
    for (int off = 1; off < 256; off <<= 1) {
        int t = (tid >= off) ? sd[tid - off] : 0;
        __syncthreads();
        sd[tid] += t;
        __syncthreads();
    }
    if (n < N) exscan[n] = sd[tid] - vp;
    if (tid == 255) blocksum[blockIdx.x] = sd[255];
}

// FUSED: blocks [0,256): fill CSR (ushort src).  Each fill block LDS-scans
//   the (<=256) blocksums -> ebs[], writes its offsets slice AND the pad
//   slots (dummy node N -> zero rows), then scatters:
//     pos = ebs[d>>8] + exscan[d] + basecum[b][d] + rank.
// blocks [256,256+GB): mfma gemm1 h1 = bf16((x @ W1t) * dinv); zeroes row N.
__global__ __launch_bounds__(256) void fill_gemm1_k(const int* __restrict__ src,
                                                    const int* __restrict__ dst, int E,
                                                    int chunk, int N,
                                                    const uchar* __restrict__ rankx,
                                                    const uchar* __restrict__ basecum,
                                                    const int* __restrict__ blocksum,
                                                    int NB,
                                                    const int* __restrict__ exscan,
                                                    const ushort16* __restrict__ degs,
                                                    int* __restrict__ offsets,
                                                    ushort16* __restrict__ csr_src,
                                                    const float* __restrict__ X,
                                                    const unsigned short* __restrict__ Wt,
                                                    const float* __restrict__ dinv,
                                                    uint32* __restrict__ Yu, int Nrows) {
    __shared__ int sd[256];
    __shared__ int ebs[256];
    __shared__ int total;
    if ((int)blockIdx.x < 256) {
        const int f   = blockIdx.x;
        const int tid = threadIdx.x;
        // ---- redundant 196-element scan of blocksums (cheap) ----
        int v = (tid < NB) ? blocksum[tid] : 0;
        sd[tid] = v;
        __syncthreads();
        for (int off = 1; off < 256; off <<= 1) {
            int t = (tid >= off) ? sd[tid - off] : 0;
            __syncthreads();
            sd[tid] += t;
            __syncthreads();
        }
        ebs[tid] = sd[tid] - v;
        if (tid == 255) total = sd[255];
        __syncthreads();
        // ---- offsets slice + pad slots for the downstream agg kernels ----
        int g = f * 256 + tid;
        if (g < N) {
            int off = ebs[g >> 8] + exscan[g];
            offsets[g] = off;
            int dg = degs[g];
            int pl = (dg + 7) & ~7;
            for (int k = dg; k < pl; ++k) csr_src[off + k] = (ushort16)N;
        } else if (g == N) {
            offsets[N] = total;
        }
        // ---- CSR scatter ----
        const int b  = f >> 1;
        const uchar* bc = basecum + (size_t)b * N;
        const int q2 = chunk >> 1;
        const int e0 = b * chunk + (f & 1) * q2;
        const int e1 = min(E, e0 + q2);
        int e = e0 + tid;
        for (; e + 768 < e1; e += 1024) {
#pragma unroll
            for (int j = 0; j < 4; ++j) {
                int ej = e + j * 256;
                int d = dst[ej];
                int pos = ebs[d >> 8] + exscan[d] + (int)bc[d] + (int)rankx[ej];
                csr_src[pos] = (ushort16)src[ej];
            }
        }
        for (; e < e1; e += 256) {
            int d = dst[e];
            int pos = ebs[d >> 8] + exscan[d] + (int)bc[d] + (int)rankx[e];
            csr_src[pos] = (ushort16)src[e];
        }
        return;
    }
    // ---- gemm1 part (NCOL=128, fp32 A converted in-register, *dinv) ----
    constexpr int NCOL = 128;
    constexpr int NT = NCOL / 16;
    const int tid  = threadIdx.x;
    const int wave = tid >> 6;
    const int lane = tid & 63;
    const int m16  = lane & 15;
    const int q    = lane >> 4;
    const int r0   = ((int)blockIdx.x - 256) * 64 + wave * 16;

    // dummy zero row N for CSR pads (one wave, once)
    if ((int)blockIdx.x == 256 && tid < 64) Yu[(size_t)Nrows * (NCOL / 2) + tid] = 0;

    int arow = r0 + m16;
    if (arow >= Nrows) arow = Nrows - 1;

    bf16x8 afrag[4];
#pragma unroll
    for (int kb = 0; kb < 4; ++kb) {
        const float* p = &X[(size_t)arow * 128 + kb * 32 + q * 8];
        float4 u0 = *(const float4*)p;
        float4 u1 = *(const float4*)(p + 4);
        bf16x8 a;
        a[0] = (short)f2bf_rne(u0.x); a[1] = (short)f2bf_rne(u0.y);
        a[2] = (short)f2bf_rne(u0.z); a[3] = (short)f2bf_rne(u0.w);
        a[4] = (short)f2bf_rne(u1.x); a[5] = (short)f2bf_rne(u1.y);
        a[6] = (short)f2bf_rne(u1.z); a[7] = (short)f2bf_rne(u1.w);
        afrag[kb] = a;
    }

    f32x4 acc[NT];
#pragma unroll
    for (int t = 0; t < NT; ++t) acc[t] = (f32x4){0.f, 0.f, 0.f, 0.f};
#pragma unroll
    for (int t = 0; t < NT; ++t) {
        const unsigned short* Bp = &Wt[(size_t)(t * 16 + m16) * 128 + q * 8];
#pragma unroll
        for (int kb = 0; kb < 4; ++kb) {
            bf16x8 bfrag = *(const bf16x8*)&Bp[kb * 32];
            acc[t] = __builtin_amdgcn_mfma_f32_16x16x32_bf16(afrag[kb], bfrag, acc[t], 0, 0, 0);
        }
    }
#pragma unroll
    for (int i = 0; i < 4; ++i) {
        int row = r0 + q * 4 + i;
        if (row < Nrows) {
            float dn = dinv[row];
#pragma unroll
            for (int u = 0; u < NT / 2; ++u)
                Yu[(size_t)row * (NCOL / 2) + u * 16 + m16] =
                    pack_bf16x2(acc[2 * u][i] * dn, acc[2 * u + 1][i] * dn);
        }
    }
}

// FUSED layer-1 aggregation + gemm2.
// 256 threads = 4 waves; wave w aggregates nodes base+4w..base+4w+3.
// CSR segments are %8-padded (pads -> zero row N) so the gather loop is
// tail-free: 16-deep then 8-deep, indices loaded as uint4 (8 per load).
// After the barrier, waves 0-1 compute the 16x64 gemm2 tile (W2t
// pair-permuted) and write h2 with dinv folded.  Block 0 zeroes h2 row N.
__global__ __launch_bounds__(256, 8) void agg1_gemm2_k(const unsigned short* __restrict__ hs,
                                                       const int* __restrict__ offsets,
                                                       const ushort16* __restrict__ csr_src,
                                                       const float* __restrict__ dinv,
                                                       const float* __restrict__ b1,
                                                       const unsigned short* __restrict__ W2t,
                                                       uint32* __restrict__ Yu, int N) {
    __shared__ uint32 srow[16 * 68];
    const int tid  = threadIdx.x;
    const int w    = tid >> 6;
    const int lane = tid & 63;
    const int base = (int)blockIdx.x * 16;
    const uint32* T = (const uint32*)hs;
    const float2 bb = ((const float2*)b1)[lane];
    // dummy zero row N of h2 for agg2's padded gathers (one wave, once)
    if (blockIdx.x == 0 && w == 2 && lane < 32) Yu[(size_t)N * 32 + lane] = 0;
#pragma unroll
    for (int which = 0; which < 4; ++which) {
        const int node = base + 4 * w + which;
        uint32 packed = 0;
        if (node < N) {
            const int start = offsets[node];
            const int end   = offsets[node + 1];
            const float dn  = dinv[node];
            float2 self = unpack_bf16x2(T[(size_t)node * 64 + lane]);
            float ax0 = self.x, ay0 = self.y;
            float ax1 = 0.f, ay1 = 0.f, ax2 = 0.f, ay2 = 0.f, ax3 = 0.f, ay3 = 0.f;
            int p = start;
            for (; p + 15 < end; p += 16) {
                uint4 ia = *(const uint4*)&csr_src[p];
                uint4 ib = *(const uint4*)&csr_src[p + 8];
                int s0 = ia.x & 0xffff, s1 = ia.x >> 16;
                int s2 = ia.y & 0xffff, s3 = ia.y >> 16;
                int s4 = ia.z & 0xffff, s5 = ia.z >> 16;
                int s6 = ia.w & 0xffff, s7 = ia.w >> 16;
                int s8 = ib.x & 0xffff, s9 = ib.x >> 16;
                int sa = ib.y & 0xffff, sb = ib.y >> 16;
                int sc = ib.z & 0xffff, sd = ib.z >> 16;
                int se = ib.w & 0xffff, sf = ib.w >> 16;
                uint32 u0 = T[(size_t)s0 * 64 + lane];
                uint32 u1 = T[(size_t)s1 * 64 + lane];
                uint32 u2 = T[(size_t)s2 * 64 + lane];
                uint32 u3 = T[(size_t)s3 * 64 + lane];
                uint32 u4 = T[(size_t)s4 * 64 + lane];
                uint32 u5 = T[(size_t)s5 * 64 + lane];
                uint32 u6 = T[(size_t)s6 * 64 + lane];
                uint32 u7 = T[(size_t)s7 * 64 + lane];
                uint32 u8 = T[(size_t)s8 * 64 + lane];
                uint32 u9 = T[(size_t)s9 * 64 + lane];
                uint32 ua = T[(size_t)sa * 64 + lane];
                uint32 ub = T[(size_t)sb * 64 + lane];
                uint32 uc = T[(size_t)sc * 64 + lane];
                uint32 ud = T[(size_t)sd * 64 + lane];
                uint32 ue = T[(size_t)se * 64 + lane];
                uint32 uf = T[(size_t)sf * 64 + lane];
                float2 f0 = unpack_bf16x2(u0), f1 = unpack_bf16x2(u1);
                float2 f2 = unpack_bf16x2(u2), f3 = unpack_bf16x2(u3);
                float2 f4 = unpack_bf16x2(u4), f5 = unpack_bf16x2(u5);
                float2 f6 = unpack_bf16x2(u6), f7 = unpack_bf16x2(u7);
                float2 f8 = unpack_bf16x2(u8), f9 = unpack_bf16x2(u9);
                float2 fa = unpack_bf16x2(ua), fb = unpack_bf16x2(ub);
                float2 fc = unpack_bf16x2(uc), fd = unpack_bf16x2(ud);
                float2 fe = unpack_bf16x2(ue), ff = unpack_bf16x2(uf);
                ax0 += (f0.x + f4.x) + (f8.x + fc.x);
                ay0 += (f0.y + f4.y) + (f8.y + fc.y);
                ax1 += (f1.x + f5.x) + (f9.x + fd.x);
                ay1 += (f1.y + f5.y) + (f9.y + fd.y);
                ax2 += (f2.x + f6.x) + (fa.x + fe.x);
                ay2 += (f2.y + f6.y) + (fa.y + fe.y);
                ax3 += (f3.x + f7.x) + (fb.x + ff.x);
                ay3 += (f3.y + f7.y) + (fb.y + ff.y);
            }
            for (; p + 7 < end; p += 8) {
                uint4 ia = *(const uint4*)&csr_src[p];
                int s0 = ia.x & 0xffff, s1 = ia.x >> 16;
                int s2 = ia.y & 0xffff, s3 = ia.y >> 16;
                int s4 = ia.z & 0xffff, s5 = ia.z >> 16;
                int s6 = ia.w & 0xffff, s7 = ia.w >> 16;
                uint32 u0 = T[(size_t)s0 * 64 + lane];
                uint32 u1 = T[(size_t)s1 * 64 + lane];
                uint32 u2 = T[(size_t)s2 * 64 + lane];
                uint32 u3 = T[(size_t)s3 * 64 + lane];
                uint32 u4 = T[(size_t)s4 * 64 + lane];
                uint32 u5 = T[(size_t)s5 * 64 + lane];
                uint32 u6 = T[(size_t)s6 * 64 + lane];
                uint32 u7 = T[(size_t)s7 * 64 + lane];
                float2 f0 = unpack_bf16x2(u0), f1 = unpack_bf16x2(u1);
                float2 f2 = unpack_bf16x2(u2), f3 = unpack_bf16x2(u3);
                float2 f4 = unpack_bf16x2(u4), f5 = unpack_bf16x2(u5);
                float2 f6 = unpack_bf16x2(u6), f7 = unpack_bf16x2(u7);
                ax0 += f0.x + f4.x; ay0 += f0.y + f4.y;
                ax1 += f1.x + f5.x; ay1 += f1.y + f5.y;
                ax2 += f2.x + f6.x; ay2 += f2.y + f6.y;
                ax3 += f3.x + f7.x; ay3 += f3.y + f7.y;
            }
            float vx = ((ax0 + ax1) + (ax2 + ax3)) * dn + bb.x;
            float vy = ((ay0 + ay1) + (ay2 + ay3)) * dn + bb.y;
            vx = vx > 0.f ? vx : 0.f;
            vy = vy > 0.f ? vy : 0.f;
            packed = pack_bf16x2(vx, vy);
        }
        srow[(4 * w + which) * 68 + lane] = packed;
    }
    __syncthreads();
    // ---- gemm2 tail: wave w<2 computes pack-pair pp=w (2 col-tiles) ----
    if (w < 2) {
        const int pp  = w;
        const int m16 = lane & 15;
        const int q   = lane >> 4;
        bf16x8 afrag[4];
#pragma unroll
        for (int kb = 0; kb < 4; ++kb)
            afrag[kb] = *(const bf16x8*)&srow[m16 * 68 + kb * 16 + q * 4];
        f32x4 acc0 = (f32x4){0.f, 0.f, 0.f, 0.f};
        f32x4 acc1 = (f32x4){0.f, 0.f, 0.f, 0.f};
        const unsigned short* Bp0 = &W2t[(size_t)((2 * pp) * 16 + m16) * 128 + q * 8];
        const unsigned short* Bp1 = &W2t[(size_t)((2 * pp + 1) * 16 + m16) * 128 + q * 8];
#pragma unroll
        for (int kb = 0; kb < 4; ++kb) {
            bf16x8 b0  = *(const bf16x8*)&Bp0[kb * 32];
            bf16x8 b1f = *(const bf16x8*)&Bp1[kb * 32];
            acc0 = __builtin_amdgcn_mfma_f32_16x16x32_bf16(afrag[kb], b0, acc0, 0, 0, 0);
            acc1 = __builtin_amdgcn_mfma_f32_16x16x32_bf16(afrag[kb], b1f, acc1, 0, 0, 0);
        }
#pragma unroll
        for (int i = 0; i < 4; ++i) {
            int row = base + q * 4 + i;
            if (row < N) {
                float dn2 = dinv[row];
                Yu[(size_t)row * 32 + pp * 16 + m16] =
                    pack_bf16x2(acc0[i] * dn2, acc1[i] * dn2);
            }
        }
    }
}

// Layer-2 aggregation + bias + log_softmax. 32 lanes/node, 8 nodes/block,
// tail-free 16/8-deep gather (padded CSR, pads -> zero row N of h2).
__global__ __launch_bounds__(256, 8) void agg2_k(const unsigned short* __restrict__ hs,
                                                 const int* __restrict__ offsets,
                                                 const ushort16* __restrict__ csr_src,
                                                 const float* __restrict__ dinv,
                                                 const float* __restrict__ b2,
                                                 float* __restrict__ out, int N) {
    const int tid  = threadIdx.x;
    const int node = blockIdx.x * 8 + (tid >> 5);
    const int l    = tid & 31;
    if (node >= N) return;
    const uint32* T = (const uint32*)hs;
    const int start = offsets[node];
    const int end   = offsets[node + 1];
    const float dn  = dinv[node];
    float2 self = unpack_bf16x2(T[(size_t)node * 32 + l]);
    float ax0 = self.x, ay0 = self.y;
    float ax1 = 0.f, ay1 = 0.f, ax2 = 0.f, ay2 = 0.f, ax3 = 0.f, ay3 = 0.f;
    int p = start;
    for (; p + 15 < end; p += 16) {
        uint4 ia = *(const uint4*)&csr_src[p];
        uint4 ib = *(const uint4*)&csr_src[p + 8];
        int s0 = ia.x & 0xffff, s1 = ia.x >> 16;
        int s2 = ia.y & 0xffff, s3 = ia.y >> 16;
        int s4 = ia.z & 0xffff, s5 = ia.z >> 16;
        int s6 = ia.w & 0xffff, s7 = ia.w >> 16;
        int s8 = ib.x & 0xffff, s9 = ib.x >> 16;
        int sa = ib.y & 0xffff, sb = ib.y >> 16;
        int sc = ib.z & 0xffff, sd = ib.z >> 16;
        int se = ib.w & 0xffff, sf = ib.w >> 16;
        uint32 u0 = T[(size_t)s0 * 32 + l];
        uint32 u1 = T[(size_t)s1 * 32 + l];
        uint32 u2 = T[(size_t)s2 * 32 + l];
        uint32 u3 = T[(size_t)s3 * 32 + l];
        uint32 u4 = T[(size_t)s4 * 32 + l];
        uint32 u5 = T[(size_t)s5 * 32 + l];
        uint32 u6 = T[(size_t)s6 * 32 + l];
        uint32 u7 = T[(size_t)s7 * 32 + l];
        uint32 u8 = T[(size_t)s8 * 32 + l];
        uint32 u9 = T[(size_t)s9 * 32 + l];
        uint32 ua = T[(size_t)sa * 32 + l];
        uint32 ub = T[(size_t)sb * 32 + l];
        uint32 uc = T[(size_t)sc * 32 + l];
        uint32 ud = T[(size_t)sd * 32 + l];
        uint32 ue = T[(size_t)se * 32 + l];
        uint32 uf = T[(size_t)sf * 32 + l];
        float2 f0 = unpack_bf16x2(u0), f1 = unpack_bf16x2(u1);
        float2 f2 = unpack_bf16x2(u2), f3 = unpack_bf16x2(u3);
        float2 f4 = unpack_bf16x2(u4), f5 = unpack_bf16x2(u5);
        float2 f6 = unpack_bf16x2(u6), f7 = unpack_bf16x2(u7);
        float2 f8 = unpack_bf16x2(u8), f9 = unpack_bf16x2(u9);
        float2 fa = unpack_bf16x2(ua), fb = unpack_bf16x2(ub);
        float2 fc = unpack_bf16x2(uc), fd = unpack_bf16x2(ud);
        float2 fe = unpack_bf16x2(ue), ff = unpack_bf16x2(uf);
        ax0 += (f0.x + f4.x) + (f8.x + fc.x);
        ay0 += (f0.y + f4.y) + (f8.y + fc.y);
        ax1 += (f1.x + f5.x) + (f9.x + fd.x);
        ay1 += (f1.y + f5.y) + (f9.y + fd.y);
        ax2 += (f2.x + f6.x) + (fa.x + fe.x);
        ay2 += (f2.y + f6.y) + (fa.y + fe.y);
        ax3 += (f3.x + f7.x) + (fb.x + ff.x);
        ay3 += (f3.y + f7.y) + (fb.y + ff.y);
    }
    for (; p + 7 < end; p += 8) {
        uint4 ia = *(const uint4*)&csr_src[p];
        int s0 = ia.x & 0xffff, s1 = ia.x >> 16;
        int s2 = ia.y & 0xffff, s3 = ia.y >> 16;
        int s4 = ia.z & 0xffff, s5 = ia.z >> 16;
        int s6 = ia.w & 0xffff, s7 = ia.w >> 16;
        uint32 u0 = T[(size_t)s0 * 32 + l];
        uint32 u1 = T[(size_t)s1 * 32 + l];
        uint32 u2 = T[(size_t)s2 * 32 + l];
        uint32 u3 = T[(size_t)s3 * 32 + l];
        uint32 u4 = T[(size_t)s4 * 32 + l];
        uint32 u5 = T[(size_t)s5 * 32 + l];
        uint32 u6 = T[(size_t)s6 * 32 + l];
        uint32 u7 = T[(size_t)s7 * 32 + l];
        float2 f0 = unpack_bf16x2(u0), f1 = unpack_bf16x2(u1);
        float2 f2 = unpack_bf16x2(u2), f3 = unpack_bf16x2(u3);
        float2 f4 = unpack_bf16x2(u4), f5 = unpack_bf16x2(u5);
        float2 f6 = unpack_bf16x2(u6), f7 = unpack_bf16x2(u7);
        ax0 += f0.x + f4.x; ay0 += f0.y + f4.y;
        ax1 += f1.x + f5.x; ay1 += f1.y + f5.y;
        ax2 += f2.x + f6.x; ay2 += f2.y + f6.y;
        ax3 += f3.x + f7.x; ay3 += f3.y + f7.y;
    }
    float2 bb = ((const float2*)b2)[l];
    float vx = ((ax0 + ax1) + (ax2 + ax3)) * dn + bb.x;
    float vy = ((ay0 + ay1) + (ay2 + ay3)) * dn + bb.y;
    float m = fmaxf(vx, vy);
#pragma unroll
    for (int off = 16; off > 0; off >>= 1) m = fmaxf(m, __shfl_xor(m, off, 64));
    float ex = __expf(vx - m) + __expf(vy - m);
    float ssum = ex;
#pragma unroll
    for (int off = 16; off > 0; off >>= 1) ssum += __shfl_xor(ssum, off, 64);
    float lse = m + __logf(ssum);
    float2 o = {vx - lse, vy - lse};
    ((float2*)out)[(size_t)node * 32 + l] = o;
}

extern "C" void kernel_launch(void* const* d_in, const int* in_sizes, int n_in,
                              void* d_out, int out_size, void* d_ws, size_t ws_size,
                              hipStream_t stream) {
    const float* x  = (const float*)d_in[0];
    const int*   ei = (const int*)d_in[1];
    const float* W1 = (const float*)d_in[2];
    const float* b1 = (const float*)d_in[3];
    const float* W2 = (const float*)d_in[4];
    const float* b2 = (const float*)d_in[5];
    float* out = (float*)d_out;

    const int N = in_sizes[0] / 128;  // 50000
    const int E = in_sizes[1] / 2;    // 800000
    const int* src = ei;
    const int* dst = ei + E;
    const int NB = (N + 255) / 256;        // 196
    const int NWb = (N + 3) / 4;           // 12500 byte-packed count words
    const int NWq = (NWb + 3) >> 2;        // 3125 words per quarter-histogram
    const int chunk = (E + NHB - 1) / NHB; // 6250 edges per hist chunk

    char* ws = (char*)d_ws;
    auto alloc = [&](size_t bytes) -> char* {
        char* p = ws;
        ws += (bytes + 255) & ~(size_t)255;
        return p;
    };
    unsigned short* h1  = (unsigned short*)alloc((size_t)(N + 1) * 128 * 2); // +zero row
    unsigned short* h2  = (unsigned short*)alloc((size_t)(N + 1) * 64 * 2);  // +zero row
    uint32* counts_pb = (uint32*)alloc((size_t)NHB * NWb * 4);               // 6.4MB
    uchar* basecum  = (uchar*)alloc((size_t)NHB * N);                        // 6.4MB
    uchar* rankx    = (uchar*)alloc((size_t)E);                              // 0.8MB
    ushort16* csr_src = (ushort16*)alloc(((size_t)E + 8 * (size_t)N) * 2);   // padded CSR
    float* dinv     = (float*)alloc((size_t)N * 4);
    int*   exscan   = (int*)alloc((size_t)N * 4);
    int*   blocksum = (int*)alloc((size_t)NB * 4);
    int*   offsets  = (int*)alloc((size_t)(N + 1) * 4);
    ushort16* degs  = (ushort16*)alloc((size_t)N * 2);
    unsigned short* W1t = (unsigned short*)alloc(128 * 128 * 2);
    unsigned short* W2t = (unsigned short*)alloc(64 * 128 * 2);

    const int GB = (N + 63) / 64;          // 782 gemm blocks
    const int CB = (128 * 128 + 64 * 128 + 255) / 256;  // 96 convw blocks

    hist_conv_k<<<4 * NHB + CB, 256, NWq * 4, stream>>>(dst, E, NWb, chunk, counts_pb,
                                                        rankx, W1, W2, W1t, W2t);
    scan2_k<<<NB, 256, 0, stream>>>(counts_pb, N, NWb, basecum, exscan, blocksum, dinv,
                                    degs);
    fill_gemm1_k<<<256 + GB, 256, 0, stream>>>(src, dst, E, chunk, N, rankx, basecum,
                                               blocksum, NB, exscan, degs, offsets,
                                               csr_src, x, W1t, dinv, (uint32*)h1, N);
    agg1_gemm2_k<<<(N + 15) / 16, 256, 0, stream>>>(h1, offsets, csr_src, dinv, b1,
                                                    W2t, (uint32*)h2, N);
    agg2_k<<<(N + 7) / 8, 256, 0, stream>>>(h2, offsets, csr_src, dinv, b2, out, N);
}